// Round 11
// baseline (307.752 us; speedup 1.0000x reference)
//
#include <hip/hip_runtime.h>
#include <hip/hip_bf16.h>

#define NT 6
#define BM 256
#define BN 256
#define BK 32
#define SLOT 16384   // shorts per ring slot: A 256x32 + B 256x32 = 32KB

typedef __attribute__((ext_vector_type(4))) float f32x4;
typedef __attribute__((ext_vector_type(8))) short bf16x8;

__device__ __forceinline__ short f2bf(float f) {
    __hip_bfloat16 h = __float2bfloat16(f);
    return (short)__builtin_bit_cast(unsigned short, h);
}

// ---- 1. segment argmax: packed (conf_bits<<32) | ~idx, atomicMax ----
__global__ void k_segmax(const float* __restrict__ conf,
                         const int* __restrict__ bidx,
                         unsigned long long* __restrict__ packed, int E) {
    int i = blockIdx.x * blockDim.x + threadIdx.x;
    if (i >= E) return;
    unsigned cb = __float_as_uint(conf[i]);
    unsigned long long p = ((unsigned long long)cb << 32) | (unsigned)(~(unsigned)i);
    atomicMax(&packed[bidx[i]], p);
}

// ---- 2. base[t][n] = emb[t] . W1[n,:d4] + b1[n]; extract conf/x/y columns ----
__global__ void k_base(const float* __restrict__ emb, const float* __restrict__ W1,
                       const float* __restrict__ b1, float* __restrict__ base,
                       float* __restrict__ vecs, int d2, int d4) {
    int gw = (blockIdx.x * blockDim.x + threadIdx.x) >> 6;
    int lane = threadIdx.x & 63;
    int t = gw / d2, n = gw % d2;
    const float* e = emb + (size_t)t * d4;
    const float* w = W1 + (size_t)n * (d4 + 3);
    float s = 0.f;
    for (int k = lane; k < d4; k += 64) s += e[k] * w[k];
#pragma unroll
    for (int m = 32; m; m >>= 1) s += __shfl_xor(s, m);
    if (lane == 0) {
        base[gw] = s + b1[n];
        if (t == 0) {
            vecs[n]          = w[d4];
            vecs[d2 + n]     = w[d4 + 1];
            vecs[2 * d2 + n] = w[d4 + 2];
        }
    }
}

// ---- 3. W2 fp32 -> bf16 ----
__global__ void k_w2cast(const float* __restrict__ W2, short* __restrict__ W2b, long n) {
    long i = ((long)blockIdx.x * blockDim.x + threadIdx.x) * 8;
    if (i >= n) return;
    bf16x8 v;
#pragma unroll
    for (int j = 0; j < 8; ++j) v[j] = f2bf(W2[i + j]);
    *(bf16x8*)(W2b + i) = v;
}

// ---- 4. h[b][n] = relu(base[t][n] + conf*cv[n] + lx*xv[n] + ly*yv[n]) -> bf16 ----
__global__ void k_h(const unsigned long long* __restrict__ packed,
                    const int* __restrict__ etype, const float* __restrict__ loc,
                    const float* __restrict__ base, const float* __restrict__ vecs,
                    float* __restrict__ mask, short* __restrict__ h, int d2) {
    int b = blockIdx.x;
    int tid = threadIdx.x;
    unsigned long long p = packed[b];
    bool has = (p != 0ULL);
    float conf = 0.f, lx = 0.f, ly = 0.f;
    int t = 0;
    if (has) {
        unsigned idx = ~(unsigned)(p & 0xFFFFFFFFu);
        conf = __uint_as_float((unsigned)(p >> 32));
        t  = etype[idx];
        lx = loc[2 * (size_t)idx]     * (1.0f / 640.0f);
        ly = loc[2 * (size_t)idx + 1] * (1.0f / 480.0f);
    }
    if (tid == 0) mask[b] = has ? 1.0f : 0.0f;
    const float* bs = base + (size_t)t * d2;
    const float* cv = vecs;
    const float* xv = vecs + d2;
    const float* yv = vecs + 2 * d2;
    int n0 = tid * 8;
    bf16x8 v;
#pragma unroll
    for (int j = 0; j < 8; ++j) {
        int n = n0 + j;
        float g = bs[n] + conf * cv[n] + lx * xv[n] + ly * yv[n];
        g = fmaxf(g, 0.f);
        v[j] = has ? f2bf(g) : (short)0;
    }
    *(bf16x8*)(h + (size_t)b * d2 + n0) = v;
}

// ---- 5. GEMM: C[M][N] = A[M][K](bf16) * Bm[N][K](bf16)^T, +b2, *mask ----
// 256x256, BK=32, 4-slot ring, 8 waves (2x4), 16x16x32 MFMA (R3-verified
// swizzle/frags/staging/epilogue).
// BARRIER EVERY 2 TILES (superstep): during superstep j (tiles 2j,2j+1),
// staging targets slots (2j+2)&3,(2j+3)&3 — disjoint from read slots
// (2j)&3,(2j+1)&3 (deltas 1,2,3 mod 4). Slot (2j+2)&3's last readers
// (tile 2j-2) finished before barrier j. Residency: tiles 2j,2j+1 staged
// in superstep j-1, drained by its trailing vmcnt(0) (issued ~2000cyc
// earlier -> free), published by barrier j. Within a superstep waves
// FREE-RUN: fast wave's tile-(t+1) ds_reads drain under slow wave's tile-t
// MFMA -> cross-wave LDS/MFMA pipe overlap that per-tile barriers forbade.

#define GLL(src, dst) __builtin_amdgcn_global_load_lds(                      \
    (const __attribute__((address_space(1))) void*)(src),                    \
    (__attribute__((address_space(3))) void*)(dst), 16, 0, 0)

#define STAGE4(slotp) do {                                                   \
    GLL(pa0, (slotp) + dA0); GLL(pa1, (slotp) + dA1);                        \
    GLL(pb0, (slotp) + dB0); GLL(pb1, (slotp) + dB1);                        \
    pa0 += BK; pa1 += BK; pb0 += BK; pb1 += BK; } while (0)

#define SB __builtin_amdgcn_sched_barrier(0)

// one K32 tile: 12 ds_read_b128 -> optional STAGE4 -> 32 MFMA
#define TILE(T) do {                                                         \
    const short* sr_ = lds + ((T) & 3) * SLOT;                               \
    bf16x8 bv[4], a03[4], a47[4];                                            \
    _Pragma("unroll") for (int n = 0; n < 4; ++n)                            \
        bv[n] = *(const bf16x8*)(sr_ + boff + n * 512);                      \
    _Pragma("unroll") for (int m = 0; m < 4; ++m)                            \
        a03[m] = *(const bf16x8*)(sr_ + aoff + m * 512);                     \
    _Pragma("unroll") for (int m = 0; m < 4; ++m)                            \
        a47[m] = *(const bf16x8*)(sr_ + aoff + 2048 + m * 512);              \
    if ((T) + 2 < KT) { short* sw_ = lds + (((T) + 2) & 3) * SLOT;           \
                        STAGE4(sw_); }                                       \
    __builtin_amdgcn_s_setprio(1);                                           \
    _Pragma("unroll") for (int m = 0; m < 4; ++m)                            \
    _Pragma("unroll") for (int n = 0; n < 4; ++n)                            \
        acc[m][n] = __builtin_amdgcn_mfma_f32_16x16x32_bf16(                 \
            a03[m], bv[n], acc[m][n], 0, 0, 0);                              \
    _Pragma("unroll") for (int m = 0; m < 4; ++m)                            \
    _Pragma("unroll") for (int n = 0; n < 4; ++n)                            \
        acc[4 + m][n] = __builtin_amdgcn_mfma_f32_16x16x32_bf16(             \
            a47[m], bv[n], acc[4 + m][n], 0, 0, 0);                          \
    __builtin_amdgcn_s_setprio(0);                                           \
} while (0)

__global__ __launch_bounds__(512, 2)
void k_gemm(const short* __restrict__ A, const short* __restrict__ Bm,
            const float* __restrict__ b2, const float* __restrict__ mask,
            float* __restrict__ C, int M, int N, int K, int nbn) {
    __shared__ __align__(16) short lds[4 * SLOT];   // 128 KiB

    int tid = threadIdx.x;
    int lane = tid & 63;
    int wave = tid >> 6;            // 0..7
    int wr = wave >> 2, wc = wave & 3;

    // XCD-aware bijective swizzle (grid = 1024, % 8 == 0)
    int bid = blockIdx.x;
    int wg = (bid & 7) * ((int)gridDim.x >> 3) + (bid >> 3);
    int bm = wg / nbn, bn = wg % nbn;
    int row0 = bm * BM, col0 = bn * BN;

    // ---- staging addresses (4 x 16B per thread per K-tile) ----
    int srow = tid >> 2;                            // 0..127
    int chunkL = (tid & 3) ^ ((srow >> 1) & 3);     // inverse-swizzled source
    const short* pa0 = A + (size_t)(row0 + srow) * K + chunkL * 8;
    const short* pa1 = pa0 + (size_t)128 * K;
    const short* pb0 = Bm + (size_t)(col0 + srow) * K + chunkL * 8;
    const short* pb1 = pb0 + (size_t)128 * K;
    int dA0 = tid * 8, dA1 = 4096 + tid * 8;
    int dB0 = 8192 + tid * 8, dB1 = 12288 + tid * 8;

    // ---- fragment read offsets (R3-verified 0-conflict pattern) ----
    int frow = lane & 15, fk = lane >> 4;
    int cp = fk ^ ((frow >> 1) & 3);                // physical chunk
    int aoff = (wr * 128 + frow) * 32 + cp * 8;
    int boff = 8192 + (wc * 64 + frow) * 32 + cp * 8;

    f32x4 acc[8][4] = {};

    int KT = K / BK;                                // 64

    // prologue: stage tiles 0,1; drain; publish
    STAGE4(lds + 0 * SLOT);
    STAGE4(lds + 1 * SLOT);
    asm volatile("s_waitcnt vmcnt(0)" ::: "memory");
    __builtin_amdgcn_s_barrier();
    SB;

#pragma unroll 1
    for (int t = 0; t < KT; t += 2) {
        TILE(t);
        TILE(t + 1);
        SB;
        if (t + 2 < KT) {
            asm volatile("s_waitcnt vmcnt(0)" ::: "memory");
            __builtin_amdgcn_s_barrier();
            SB;
        }
    }

    // ---- epilogue: +b2, *mask ----
#pragma unroll
    for (int m = 0; m < 8; ++m) {
        int rbase = row0 + wr * 128 + m * 16 + (lane >> 4) * 4;
#pragma unroll
        for (int j = 0; j < 4; ++j) {
            int r = rbase + j;
            float mk = mask[r];
#pragma unroll
            for (int n = 0; n < 4; ++n) {
                int c = col0 + wc * 64 + n * 16 + frow;
                C[(size_t)r * N + c] = (acc[m][n][j] + b2[c]) * mk;
            }
        }
    }
}

extern "C" void kernel_launch(void* const* d_in, const int* in_sizes, int n_in,
                              void* d_out, int out_size, void* d_ws, size_t ws_size,
                              hipStream_t stream) {
    const int* etype   = (const int*)d_in[0];
    const float* conf  = (const float*)d_in[1];
    const float* loc   = (const float*)d_in[2];
    const int* bidx    = (const int*)d_in[3];
    const float* emb   = (const float*)d_in[5];
    const float* W1    = (const float*)d_in[6];
    const float* b1    = (const float*)d_in[7];
    const float* W2    = (const float*)d_in[8];
    const float* b2    = (const float*)d_in[9];
    float* out = (float*)d_out;

    int E  = in_sizes[0];
    int d2 = in_sizes[7];           // 2048
    int d  = in_sizes[9];           // 4096
    int d4 = in_sizes[5] / NT;      // 1024
    int B  = out_size / d;          // 16384

    char* ws = (char*)d_ws;
    unsigned long long* packed = (unsigned long long*)ws;     // B*8
    float* mask = (float*)(ws + (size_t)B * 8);               // B*4
    float* base = mask + B;                                   // NT*d2
    float* vecs = base + NT * d2;                             // 3*d2
    short* w2b  = (short*)(vecs + 3 * d2);                    // d*d2 bf16
    short* h    = w2b + (size_t)d * d2;                       // B*d2 bf16

    hipMemsetAsync(packed, 0, (size_t)B * 8, stream);
    k_segmax<<<(E + 255) / 256, 256, 0, stream>>>(conf, bidx, packed, E);
    k_base<<<(NT * d2) / 4, 256, 0, stream>>>(emb, W1, b1, base, vecs, d2, d4);
    long nw2 = (long)d * d2;
    k_w2cast<<<(int)(nw2 / 8 / 256), 256, 0, stream>>>(W2, w2b, nw2);
    k_h<<<B, 256, 0, stream>>>(packed, etype, loc, base, vecs, mask, h, d2);
    int nbm = B / BM, nbn = d / BN;
    k_gemm<<<dim3(nbm * nbn), dim3(512), 0, stream>>>(h, w2b, b2, mask, out, B, d, d2, nbn);
}